// Round 2
// baseline (738.138 us; speedup 1.0000x reference)
//
#include <hip/hip_runtime.h>
#include <math.h>

typedef __attribute__((ext_vector_type(8))) short bf16x8;
typedef __attribute__((ext_vector_type(4))) float f32x4;
typedef __attribute__((ext_vector_type(4))) short s16x4;

#define NBATCH 4
#define NPTS   4096
#define NTOT   (NBATCH*NPTS)   // 16384

__device__ __forceinline__ float bf2f(unsigned short h){
  unsigned int u = ((unsigned int)h) << 16;
  return __builtin_bit_cast(float, u);
}
__device__ __forceinline__ unsigned short f2bf(float f){
  unsigned int u = __builtin_bit_cast(unsigned int, f);
  u += 0x7FFFu + ((u >> 16) & 1u);   // RNE
  return (unsigned short)(u >> 16);
}

// byte offset into a [row][256 bf16] LDS tile (512B row stride), XOR-swizzled
__device__ __forceinline__ unsigned int swz(int row, int kbyte){
  return (unsigned int)(row * 512) + (((unsigned int)kbyte) ^ (((unsigned int)row & 7u) << 4));
}

#define MFMA(a,b,c) __builtin_amdgcn_mfma_f32_16x16x32_bf16((a),(b),(c),0,0,0)

// ---------------- prep: features -> bf16 ----------------
__global__ __launch_bounds__(256) void k_convert(const float* __restrict__ x,
                                                 unsigned short* __restrict__ xb, int n){
  int i = (blockIdx.x * 256 + threadIdx.x) * 4;
  if (i < n){
    float4 v = *(const float4*)(x + i);
    s16x4 o;
    o[0] = (short)f2bf(v.x); o[1] = (short)f2bf(v.y);
    o[2] = (short)f2bf(v.z); o[3] = (short)f2bf(v.w);
    *(s16x4*)(xb + i) = o;
  }
}

// ---------------- prep: transposed bf16 weight copies ----------------
__global__ __launch_bounds__(256) void k_prep_mats(
    const float* __restrict__ fc1w, const float* __restrict__ scw,
    const float* __restrict__ wv,  const float* __restrict__ g2,
    const float* __restrict__ fc2, const float* __restrict__ W2,
    unsigned short* __restrict__ fc1scT, unsigned short* __restrict__ qkvT,
    unsigned short* __restrict__ g2sT, unsigned short* __restrict__ fc2T,
    unsigned short* __restrict__ BposT){
  int c = blockIdx.x, d = threadIdx.x;
  fc1scT[c*256 + d]       = f2bf(fc1w[d*256 + c]);
  fc1scT[(256+c)*256 + d] = f2bf(scw[d*256 + c]);
  qkvT[(512+c)*256 + d]   = f2bf(wv[d*256 + c]);
  g2sT[c*256 + d]         = f2bf(g2[d*256 + c] * 0.0625f);   // fold 1/sqrt(DM)=1/16
  fc2T[c*256 + d]         = f2bf(fc2[d*256 + c]);
  BposT[(256+c)*256 + d]  = f2bf(W2[d*256 + c]);
}

// ---------------- prep: folded weight GEMMs (256x256x256, tiny) ----------------
__global__ __launch_bounds__(256) void k_prep_gemm(
    const float* __restrict__ wq, const float* __restrict__ wk,
    const float* __restrict__ g1, const float* __restrict__ W2,
    const float* __restrict__ b2d, const float* __restrict__ gb1,
    unsigned short* __restrict__ qkvT, unsigned short* __restrict__ BposT,
    float* __restrict__ c1){
  int c = threadIdx.x, bid = blockIdx.x;
  if (bid < 256){                       // WqgT[c][d] = sum_e wq[d][e] g1[e][c]
    int d = bid; float acc = 0.f;
    for (int e=0;e<256;e++) acc += wq[d*256+e]*g1[e*256+c];
    qkvT[c*256 + d] = f2bf(acc);
  } else if (bid < 512){                // WkgT
    int d = bid-256; float acc = 0.f;
    for (int e=0;e<256;e++) acc += wk[d*256+e]*g1[e*256+c];
    qkvT[(256+c)*256 + d] = f2bf(acc);
  } else if (bid < 768){                // W2g1T -> BposT rows 0..255
    int d = bid-512; float acc = 0.f;
    for (int e=0;e<256;e++) acc += W2[d*256+e]*g1[e*256+c];
    BposT[c*256 + d] = f2bf(acc);
  } else {                              // c1 = b2d @ g1 + gb1
    float acc = 0.f;
    for (int e=0;e<256;e++) acc += b2d[e]*g1[e*256+c];
    c1[c] = acc + gb1[c];
  }
}

// ---------------- kNN: one wave per point, all-static register top16 ----------------
__global__ __launch_bounds__(256) void k_knn(const float* __restrict__ xyz,
                                             int* __restrict__ knn){
  int wave = threadIdx.x >> 6, lane = threadIdx.x & 63;
  int widx = blockIdx.x * 4 + wave;           // 0..16383
  int b = widx >> 12, n = widx & 4095;
  const float* xb = xyz + (size_t)b * NPTS * 3;
  float px = xb[n*3+0], py = xb[n*3+1], pz = xb[n*3+2];
  float x2n = px*px + py*py + pz*pz;
  float dist[16]; int didx[16];
  #pragma unroll
  for (int i=0;i<16;i++){ dist[i] = 3.4e38f; didx[i] = -1; }
  float cmax = 3.4e38f; int cslot = 0;
  for (int t=0;t<64;t++){
    int m = t*64 + lane;                      // lanes own disjoint candidate sets
    float qx = xb[m*3+0], qy = xb[m*3+1], qz = xb[m*3+2];
    float x2m = qx*qx + qy*qy + qz*qz;
    float dot = px*qx + py*qy + pz*qz;
    float d = x2n + x2m - 2.0f*dot;           // same formula as reference
    if (d < cmax){
      #pragma unroll
      for (int i=0;i<16;i++){                 // static predicated insert (no scratch)
        bool hit = (i == cslot);
        dist[i] = hit ? d : dist[i];
        didx[i] = hit ? m : didx[i];
      }
      cmax = dist[0]; cslot = 0;
      #pragma unroll
      for (int i=1;i<16;i++){
        bool g = dist[i] > cmax;
        cmax  = g ? dist[i] : cmax;
        cslot = g ? i : cslot;
      }
    }
  }
  int keep = -1;
  for (int r=0;r<16;r++){
    float lv = dist[0]; int li = didx[0], ls = 0;
    #pragma unroll
    for (int i=1;i<16;i++){
      bool lt = (dist[i] < lv) || (dist[i] == lv && didx[i] < li);
      lv = lt ? dist[i] : lv; li = lt ? didx[i] : li; ls = lt ? i : ls;
    }
    float gv = lv; int gi = li;
    #pragma unroll
    for (int off=32; off>=1; off>>=1){
      float ov = __shfl_xor(gv, off, 64);
      int   oi = __shfl_xor(gi, off, 64);
      if (ov < gv || (ov == gv && oi < gi)){ gv = ov; gi = oi; }
    }
    if (gi == li){
      #pragma unroll
      for (int i=0;i<16;i++) if (i == ls) dist[i] = 3.4e38f;   // static pop
    }
    if (lane == r) keep = gi;
  }
  if (lane < 16) knn[(size_t)widx*16 + lane] = keep;
}

// ---------------- flat GEMM: C(16384 x N) = A(16384x256,bf16) @ BT^T ----------------
template<int MODE>
__global__ __launch_bounds__(256) void k_gemm(
    const unsigned short* __restrict__ A, const unsigned short* __restrict__ BT,
    const float* __restrict__ bias0, const float* __restrict__ bias1,
    unsigned short* __restrict__ out0, unsigned short* __restrict__ out1,
    unsigned short* __restrict__ out2, const unsigned short* __restrict__ scbuf,
    float* __restrict__ fout){
  __shared__ unsigned short As[128*40];
  __shared__ unsigned short Bs[128*40];
  int m0 = blockIdx.x * 128, n0 = blockIdx.y * 128;
  int t = threadIdx.x;
  int lane = t & 63, wave = t >> 6, wm = wave >> 1, wn = wave & 1;
  int lrow = lane & 15, lkg = lane >> 4;
  f32x4 acc[4][4] = {};
  for (int k0 = 0; k0 < 256; k0 += 32){
    int r = t >> 1, h = t & 1;
    const bf16x8* ga = (const bf16x8*)(A  + (size_t)(m0 + r)*256 + k0 + h*16);
    const bf16x8* gb = (const bf16x8*)(BT + (size_t)(n0 + r)*256 + k0 + h*16);
    bf16x8 a0 = ga[0], a1 = ga[1], b0 = gb[0], b1 = gb[1];
    *(bf16x8*)&As[r*40 + h*16]     = a0;
    *(bf16x8*)&As[r*40 + h*16 + 8] = a1;
    *(bf16x8*)&Bs[r*40 + h*16]     = b0;
    *(bf16x8*)&Bs[r*40 + h*16 + 8] = b1;
    __syncthreads();
    bf16x8 af[4], bfr[4];
    #pragma unroll
    for (int fi=0; fi<4; fi++){
      af[fi]  = *(const bf16x8*)&As[(wm*64 + fi*16 + lrow)*40 + lkg*8];
      bfr[fi] = *(const bf16x8*)&Bs[(wn*64 + fi*16 + lrow)*40 + lkg*8];
    }
    #pragma unroll
    for (int fi=0; fi<4; fi++)
      #pragma unroll
      for (int nf=0; nf<4; nf++)
        acc[fi][nf] = MFMA(af[fi], bfr[nf], acc[fi][nf]);
    __syncthreads();
  }
  #pragma unroll
  for (int fi=0; fi<4; fi++)
    #pragma unroll
    for (int nf=0; nf<4; nf++)
      #pragma unroll
      for (int r=0; r<4; r++){
        int row = m0 + wm*64 + fi*16 + lkg*4 + r;
        int col = n0 + wn*64 + nf*16 + lrow;
        float v = acc[fi][nf][r];
        if (MODE == 0){
          if (col < 256) out0[(size_t)row*256 + col]       = f2bf(v + bias0[col]);
          else           out1[(size_t)row*256 + col - 256] = f2bf(v + bias1[col-256]);
        } else if (MODE == 1){
          if (col < 256)      out0[(size_t)row*256 + col]       = f2bf(v);
          else if (col < 512) out1[(size_t)row*256 + col - 256] = f2bf(v);
          else                out2[(size_t)row*256 + col - 512] = f2bf(v);
        } else {
          fout[(size_t)row*256 + col] = v + bias0[col] + bf2f(scbuf[(size_t)row*256 + col]);
        }
      }
}

// ================= stage C helpers (fi-half passes, FI0 in {0,4}) =================
template<int FI0>
__device__ __forceinline__ void mfma_pass(const char* HsB, const unsigned short* __restrict__ BT,
                                          int lrow, int lkg, int colbase, f32x4 (&acc)[4][2]){
  for (int k0 = 0; k0 < 256; k0 += 32){
    bf16x8 af[4];
    #pragma unroll
    for (int fi=0; fi<4; fi++)
      af[fi] = *(const bf16x8*)(HsB + swz((FI0+fi)*16 + lrow, k0*2 + lkg*16));
    bf16x8 bf2[2];
    #pragma unroll
    for (int nf=0; nf<2; nf++)
      bf2[nf] = *(const bf16x8*)(BT + (size_t)(colbase + nf*16 + lrow)*256 + k0 + lkg*8);
    #pragma unroll
    for (int fi=0; fi<4; fi++){
      acc[fi][0] = MFMA(af[fi], bf2[0], acc[fi][0]);
      acc[fi][1] = MFMA(af[fi], bf2[1], acc[fi][1]);
    }
  }
}

// ---------------- stage C: fused per-point transformer core ----------------
// 512 thr (8 waves), 8 points -> M=128 rows. wave w owns cols [32w,32w+32).
// LDS 79360B -> 2 blocks/CU; peak regs ~110 -> 4 waves/SIMD.
__global__ __launch_bounds__(512, 4) void k_stagec(
    const float* __restrict__ xyz, const int* __restrict__ knn,
    const unsigned short* __restrict__ qgbuf, const unsigned short* __restrict__ kgbuf,
    const unsigned short* __restrict__ vbuf,
    const unsigned short* __restrict__ BposT, const unsigned short* __restrict__ g2sT,
    const float* __restrict__ W1, const float* __restrict__ b1d,
    const float* __restrict__ b2d, const float* __restrict__ c1,
    const float* __restrict__ gb2,
    unsigned short* __restrict__ resbuf){
  extern __shared__ char smem[];
  char*           HsB   = smem;                              // 64KB H, later A2 (aliased)
  unsigned short* qgs   = (unsigned short*)(smem + 65536);   // 4KB
  float*          rels  = (float*)(smem + 69632);            // 2KB   (dead after phase1)
  float*          W1s   = (float*)(smem + 71680);            // 3KB   (dead after phase1)
  unsigned short* resSb = (unsigned short*)(smem + 69632);   // 4KB bf16 (alias, used phase4+)
  float*          b1s   = (float*)(smem + 74752);
  float*          c1s   = (float*)(smem + 75776);
  float*          b2s   = (float*)(smem + 76800);
  float*          gb2s  = (float*)(smem + 77824);
  int*            gidx  = (int*)(smem + 78848);              // 512B

  int t = threadIdx.x;
  int lane = t & 63, wn = t >> 6;
  int lrow = lane & 15, lkg = lane >> 4;
  int colbase = 32*wn;
  int tile = blockIdx.x;
  int b = tile >> 9;
  int n0 = (tile & 511) * 8;
  int g0 = b*NPTS + n0;

  // ---- phase 0 ----
  for (int i = t; i < 768; i += 512) W1s[i] = W1[i];
  if (t < 256){ b1s[t] = b1d[t]; c1s[t] = c1[t]; b2s[t] = b2d[t]; gb2s[t] = gb2[t]*0.0625f; }
  if (t < 128){
    int p = t >> 4, kk = t & 15;
    int id = knn[(size_t)(g0 + p)*16 + kk];
    gidx[t] = b*NPTS + id;
    const float* cp  = xyz + (size_t)(b*NPTS + n0 + p)*3;
    const float* np_ = xyz + (size_t)(b*NPTS + id)*3;
    rels[t*4+0] = cp[0]-np_[0]; rels[t*4+1] = cp[1]-np_[1]; rels[t*4+2] = cp[2]-np_[2];
  }
  { int e = t * 4; int p = e >> 8, c = e & 255;
    *(s16x4*)&qgs[e] = *(const s16x4*)&qgbuf[(size_t)(g0 + p)*256 + c]; }
  __syncthreads();

  // ---- phase 1: H = relu(rel @ W1 + b1) ----
  {
    int r = t >> 2, c0 = (t & 3) * 64;
    float rx = rels[r*4], ry = rels[r*4+1], rz = rels[r*4+2];
    for (int cc = 0; cc < 64; cc += 8){
      int c = c0 + cc;
      bf16x8 hv;
      #pragma unroll
      for (int j=0;j<8;j++){
        float h = rx*W1s[c+j] + ry*W1s[256+c+j] + rz*W1s[512+c+j] + b1s[c+j];
        hv[j] = (short)f2bf(fmaxf(h, 0.0f));
      }
      *(bf16x8*)(HsB + swz(r, c*2)) = hv;
    }
  }
  __syncthreads();                                   // B1: H visible

  // ---- pe = H @ W2 + b2, packed to 32 bf16-pair VGPRs ----
  unsigned int peP[32];
  {
    f32x4 acce[4][2] = {};
    mfma_pass<0>(HsB, BposT + (size_t)256*256, lrow, lkg, colbase, acce);
    #pragma unroll
    for (int fi=0; fi<4; fi++)
      #pragma unroll
      for (int nf=0; nf<2; nf++){
        int col = colbase + nf*16 + lrow;
        #pragma unroll
        for (int rp=0; rp<2; rp++){
          unsigned int lo = f2bf(acce[fi][nf][2*rp]   + b2s[col]);
          unsigned int hi = f2bf(acce[fi][nf][2*rp+1] + b2s[col]);
          peP[fi*4 + nf*2 + rp] = lo | (hi << 16);
        }
      }
  }
  {
    f32x4 acce[4][2] = {};
    mfma_pass<4>(HsB, BposT + (size_t)256*256, lrow, lkg, colbase, acce);
    #pragma unroll
    for (int fi=0; fi<4; fi++)
      #pragma unroll
      for (int nf=0; nf<2; nf++){
        int col = colbase + nf*16 + lrow;
        #pragma unroll
        for (int rp=0; rp<2; rp++){
          unsigned int lo = f2bf(acce[fi][nf][2*rp]   + b2s[col]);
          unsigned int hi = f2bf(acce[fi][nf][2*rp+1] + b2s[col]);
          peP[16 + fi*4 + nf*2 + rp] = lo | (hi << 16);
        }
      }
  }

  // ---- a1 half 0: posg rows 0-63 ----
  {
    f32x4 accg[4][2] = {};
    mfma_pass<0>(HsB, BposT, lrow, lkg, colbase, accg);
    __syncthreads();                                 // B2: all reads of H rows 0-63 done
    #pragma unroll
    for (int fi=0; fi<4; fi++)
      #pragma unroll
      for (int nf=0; nf<2; nf++)
        #pragma unroll
        for (int r=0; r<4; r++){
          int row = fi*16 + lkg*4 + r;
          int col = colbase + nf*16 + lrow;
          float a1 = accg[fi][nf][r] + bf2f(qgs[fi*256 + col])
                   - bf2f(kgbuf[(size_t)gidx[row]*256 + col]) + c1s[col];
          *(unsigned short*)(HsB + swz(row, col*2)) = f2bf(fmaxf(a1, 0.0f));
        }
  }
  // ---- a1 half 1: posg rows 64-127 (H rows 64-127 still intact) ----
  f32x4 accg2[4][2] = {};
  mfma_pass<4>(HsB, BposT, lrow, lkg, colbase, accg2);
  __syncthreads();                                   // B3: A2 rows0-63 visible; H rows64-127 read-done
  #pragma unroll
  for (int fi=0; fi<4; fi++)
    #pragma unroll
    for (int nf=0; nf<2; nf++)
      #pragma unroll
      for (int r=0; r<4; r++){
        int row = (4+fi)*16 + lkg*4 + r;
        int col = colbase + nf*16 + lrow;
        float a1 = accg2[fi][nf][r] + bf2f(qgs[(4+fi)*256 + col])
                 - bf2f(kgbuf[(size_t)gidx[row]*256 + col]) + c1s[col];
        *(unsigned short*)(HsB + swz(row, col*2)) = f2bf(fmaxf(a1, 0.0f));
      }

  // ---- GEMM2 + softmax + res, half 0 (A2 rows 0-63, points 0-3) ----
  {
    f32x4 acc2[4][2] = {};
    mfma_pass<0>(HsB, g2sT, lrow, lkg, colbase, acc2);
    #pragma unroll
    for (int fi=0; fi<4; fi++)
      #pragma unroll
      for (int nf=0; nf<2; nf++){
        int col = colbase + nf*16 + lrow;
        float s[4], e[4];
        #pragma unroll
        for (int r=0;r<4;r++) s[r] = acc2[fi][nf][r] + gb2s[col];
        float mx = fmaxf(fmaxf(s[0],s[1]), fmaxf(s[2],s[3]));
        mx = fmaxf(mx, __shfl_xor(mx, 16, 64));
        mx = fmaxf(mx, __shfl_xor(mx, 32, 64));
        float sm = 0.f;
        #pragma unroll
        for (int r=0;r<4;r++){ e[r] = __expf(s[r]-mx); sm += e[r]; }
        sm += __shfl_xor(sm, 16, 64);
        sm += __shfl_xor(sm, 32, 64);
        float rs = 1.0f / sm;
        float tsum = 0.f;
        #pragma unroll
        for (int r=0;r<4;r++){
          int row = fi*16 + lkg*4 + r;
          unsigned int pw = peP[fi*4 + nf*2 + (r>>1)];
          float pe = bf2f((unsigned short)((r&1) ? (pw>>16) : (pw & 0xffff)));
          float vv = bf2f(vbuf[(size_t)gidx[row]*256 + col]) + pe;
          tsum += (e[r]*rs) * vv;
        }
        tsum += __shfl_xor(tsum, 16, 64);
        tsum += __shfl_xor(tsum, 32, 64);
        if (lkg == 0) resSb[fi*256 + col] = f2bf(tsum);
      }
  }
  __syncthreads();                                   // B4: A2 rows64-127 visible
  // ---- GEMM2 + softmax + res, half 1 (points 4-7) ----
  {
    f32x4 acc2[4][2] = {};
    mfma_pass<4>(HsB, g2sT, lrow, lkg, colbase, acc2);
    #pragma unroll
    for (int fi=0; fi<4; fi++)
      #pragma unroll
      for (int nf=0; nf<2; nf++){
        int col = colbase + nf*16 + lrow;
        float s[4], e[4];
        #pragma unroll
        for (int r=0;r<4;r++) s[r] = acc2[fi][nf][r] + gb2s[col];
        float mx = fmaxf(fmaxf(s[0],s[1]), fmaxf(s[2],s[3]));
        mx = fmaxf(mx, __shfl_xor(mx, 16, 64));
        mx = fmaxf(mx, __shfl_xor(mx, 32, 64));
        float sm = 0.f;
        #pragma unroll
        for (int r=0;r<4;r++){ e[r] = __expf(s[r]-mx); sm += e[r]; }
        sm += __shfl_xor(sm, 16, 64);
        sm += __shfl_xor(sm, 32, 64);
        float rs = 1.0f / sm;
        float tsum = 0.f;
        #pragma unroll
        for (int r=0;r<4;r++){
          int row = (4+fi)*16 + lkg*4 + r;
          unsigned int pw = peP[16 + fi*4 + nf*2 + (r>>1)];
          float pe = bf2f((unsigned short)((r&1) ? (pw>>16) : (pw & 0xffff)));
          float vv = bf2f(vbuf[(size_t)gidx[row]*256 + col]) + pe;
          tsum += (e[r]*rs) * vv;
        }
        tsum += __shfl_xor(tsum, 16, 64);
        tsum += __shfl_xor(tsum, 32, 64);
        if (lkg == 0) resSb[(4+fi)*256 + col] = f2bf(tsum);
      }
  }
  __syncthreads();                                   // B5

  // ---- store res (bf16) ----
  { int e = t * 4; int p = e >> 8, c = e & 255;
    *(s16x4*)&resbuf[(size_t)(g0 + p)*256 + c] = *(s16x4*)&resSb[e]; }
}

// ---------------- host ----------------
extern "C" void kernel_launch(void* const* d_in, const int* in_sizes, int n_in,
                              void* d_out, int out_size, void* d_ws, size_t ws_size,
                              hipStream_t stream){
  (void)in_sizes; (void)n_in; (void)out_size; (void)ws_size;
  const float* xyz  = (const float*)d_in[0];
  const float* feat = (const float*)d_in[1];
  const float* W1   = (const float*)d_in[2];
  const float* b1d  = (const float*)d_in[3];
  const float* W2   = (const float*)d_in[4];
  const float* b2d  = (const float*)d_in[5];
  const float* fc1w = (const float*)d_in[6];
  const float* fc1b = (const float*)d_in[7];
  const float* wq   = (const float*)d_in[8];
  const float* wk   = (const float*)d_in[9];
  const float* wv   = (const float*)d_in[10];
  const float* g1   = (const float*)d_in[11];
  const float* gb1  = (const float*)d_in[12];
  const float* g2   = (const float*)d_in[13];
  const float* gb2  = (const float*)d_in[14];
  const float* fc2w = (const float*)d_in[15];
  const float* fc2b = (const float*)d_in[16];
  const float* scw  = (const float*)d_in[17];
  const float* scb  = (const float*)d_in[18];

  char* ws = (char*)d_ws;
  size_t off = 0;
  auto alloc = [&](size_t bytes)->void*{ void* p = ws + off; off += (bytes + 255) & ~(size_t)255; return p; };
  int*            knn    = (int*)alloc((size_t)NTOT*16*4);
  unsigned short* Xb     = (unsigned short*)alloc((size_t)NTOT*256*2); // reused as res
  unsigned short* fbuf   = (unsigned short*)alloc((size_t)NTOT*256*2);
  unsigned short* qg     = (unsigned short*)alloc((size_t)NTOT*256*2);
  unsigned short* kg     = (unsigned short*)alloc((size_t)NTOT*256*2);
  unsigned short* vbuf   = (unsigned short*)alloc((size_t)NTOT*256*2);
  unsigned short* scbuf  = (unsigned short*)alloc((size_t)NTOT*256*2);
  unsigned short* fc1scT = (unsigned short*)alloc(512*256*2);
  unsigned short* qkvT   = (unsigned short*)alloc(768*256*2);
  unsigned short* BposT  = (unsigned short*)alloc(512*256*2);
  unsigned short* g2sT   = (unsigned short*)alloc(256*256*2);
  unsigned short* fc2T   = (unsigned short*)alloc(256*256*2);
  float*          c1     = (float*)alloc(256*4);
  unsigned short* res    = Xb;   // alias: Xb dead after B1

  k_convert<<<4096, 256, 0, stream>>>(feat, Xb, NTOT*256);
  k_prep_mats<<<256, 256, 0, stream>>>(fc1w, scw, wv, g2, fc2w, W2, fc1scT, qkvT, g2sT, fc2T, BposT);
  k_prep_gemm<<<769, 256, 0, stream>>>(wq, wk, g1, W2, b2d, gb1, qkvT, BposT, c1);
  k_knn<<<4096, 256, 0, stream>>>(xyz, knn);
  k_gemm<0><<<dim3(128,4), 256, 0, stream>>>(Xb, fc1scT, fc1b, scb, fbuf, scbuf, nullptr, nullptr, nullptr);
  k_gemm<1><<<dim3(128,6), 256, 0, stream>>>(fbuf, qkvT, nullptr, nullptr, qg, kg, vbuf, nullptr, nullptr);
  hipFuncSetAttribute((const void*)k_stagec, hipFuncAttributeMaxDynamicSharedMemorySize, 79360);
  k_stagec<<<2048, 512, 79360, stream>>>(xyz, knn, qg, kg, vbuf, BposT, g2sT, W1, b1d, b2d, c1, gb2, res);
  k_gemm<2><<<dim3(128,2), 256, 0, stream>>>(res, fc2T, fc2b, nullptr, nullptr, nullptr, nullptr, scbuf, (float*)d_out);
}

// Round 3
// 657.417 us; speedup vs baseline: 1.1228x; 1.1228x over previous
//
#include <hip/hip_runtime.h>
#include <math.h>

typedef __attribute__((ext_vector_type(8))) short bf16x8;
typedef __attribute__((ext_vector_type(4))) float f32x4;
typedef __attribute__((ext_vector_type(4))) short s16x4;

#define NBATCH 4
#define NPTS   4096
#define NTOT   (NBATCH*NPTS)   // 16384

__device__ __forceinline__ float bf2f(unsigned short h){
  unsigned int u = ((unsigned int)h) << 16;
  return __builtin_bit_cast(float, u);
}
__device__ __forceinline__ unsigned short f2bf(float f){
  unsigned int u = __builtin_bit_cast(unsigned int, f);
  u += 0x7FFFu + ((u >> 16) & 1u);   // RNE
  return (unsigned short)(u >> 16);
}

// byte offset into a [row][256 bf16] LDS tile (512B row stride), XOR-swizzled
__device__ __forceinline__ unsigned int swz(int row, int kbyte){
  return (unsigned int)(row * 512) + (((unsigned int)kbyte) ^ (((unsigned int)row & 7u) << 4));
}

#define MFMA(a,b,c) __builtin_amdgcn_mfma_f32_16x16x32_bf16((a),(b),(c),0,0,0)

// ---------------- prep: features -> bf16 ----------------
__global__ __launch_bounds__(256) void k_convert(const float* __restrict__ x,
                                                 unsigned short* __restrict__ xb, int n){
  int i = (blockIdx.x * 256 + threadIdx.x) * 4;
  if (i < n){
    float4 v = *(const float4*)(x + i);
    s16x4 o;
    o[0] = (short)f2bf(v.x); o[1] = (short)f2bf(v.y);
    o[2] = (short)f2bf(v.z); o[3] = (short)f2bf(v.w);
    *(s16x4*)(xb + i) = o;
  }
}

// ---------------- prep: transposed bf16 weight copies ----------------
__global__ __launch_bounds__(256) void k_prep_mats(
    const float* __restrict__ fc1w, const float* __restrict__ scw,
    const float* __restrict__ wv,  const float* __restrict__ g2,
    const float* __restrict__ fc2, const float* __restrict__ W2,
    unsigned short* __restrict__ fc1scT, unsigned short* __restrict__ qkvT,
    unsigned short* __restrict__ g2sT, unsigned short* __restrict__ fc2T,
    unsigned short* __restrict__ BposT){
  int c = blockIdx.x, d = threadIdx.x;
  fc1scT[c*256 + d]       = f2bf(fc1w[d*256 + c]);
  fc1scT[(256+c)*256 + d] = f2bf(scw[d*256 + c]);
  qkvT[(512+c)*256 + d]   = f2bf(wv[d*256 + c]);
  g2sT[c*256 + d]         = f2bf(g2[d*256 + c] * 0.0625f);   // fold 1/sqrt(DM)=1/16
  fc2T[c*256 + d]         = f2bf(fc2[d*256 + c]);
  BposT[(256+c)*256 + d]  = f2bf(W2[d*256 + c]);
}

// ---------------- prep: folded weight GEMMs (256x256x256, tiny) ----------------
__global__ __launch_bounds__(256) void k_prep_gemm(
    const float* __restrict__ wq, const float* __restrict__ wk,
    const float* __restrict__ g1, const float* __restrict__ W2,
    const float* __restrict__ b2d, const float* __restrict__ gb1,
    unsigned short* __restrict__ qkvT, unsigned short* __restrict__ BposT,
    float* __restrict__ c1){
  int c = threadIdx.x, bid = blockIdx.x;
  if (bid < 256){                       // WqgT[c][d] = sum_e wq[d][e] g1[e][c]
    int d = bid; float acc = 0.f;
    for (int e=0;e<256;e++) acc += wq[d*256+e]*g1[e*256+c];
    qkvT[c*256 + d] = f2bf(acc);
  } else if (bid < 512){                // WkgT
    int d = bid-256; float acc = 0.f;
    for (int e=0;e<256;e++) acc += wk[d*256+e]*g1[e*256+c];
    qkvT[(256+c)*256 + d] = f2bf(acc);
  } else if (bid < 768){                // W2g1T -> BposT rows 0..255
    int d = bid-512; float acc = 0.f;
    for (int e=0;e<256;e++) acc += W2[d*256+e]*g1[e*256+c];
    BposT[c*256 + d] = f2bf(acc);
  } else {                              // c1 = b2d @ g1 + gb1
    float acc = 0.f;
    for (int e=0;e<256;e++) acc += b2d[e]*g1[e*256+c];
    c1[c] = acc + gb1[c];
  }
}

// ---------------- kNN: one wave per point, all-static register top16 ----------------
__global__ __launch_bounds__(256) void k_knn(const float* __restrict__ xyz,
                                             int* __restrict__ knn){
  int wave = threadIdx.x >> 6, lane = threadIdx.x & 63;
  int widx = blockIdx.x * 4 + wave;           // 0..16383
  int b = widx >> 12, n = widx & 4095;
  const float* xb = xyz + (size_t)b * NPTS * 3;
  float px = xb[n*3+0], py = xb[n*3+1], pz = xb[n*3+2];
  float x2n = px*px + py*py + pz*pz;
  float dist[16]; int didx[16];
  #pragma unroll
  for (int i=0;i<16;i++){ dist[i] = 3.4e38f; didx[i] = -1; }
  float cmax = 3.4e38f; int cslot = 0;
  for (int t=0;t<64;t++){
    int m = t*64 + lane;                      // lanes own disjoint candidate sets
    float qx = xb[m*3+0], qy = xb[m*3+1], qz = xb[m*3+2];
    float x2m = qx*qx + qy*qy + qz*qz;
    float dot = px*qx + py*qy + pz*qz;
    float d = x2n + x2m - 2.0f*dot;           // same formula as reference
    if (d < cmax){
      #pragma unroll
      for (int i=0;i<16;i++){                 // static predicated insert (no scratch)
        bool hit = (i == cslot);
        dist[i] = hit ? d : dist[i];
        didx[i] = hit ? m : didx[i];
      }
      cmax = dist[0]; cslot = 0;
      #pragma unroll
      for (int i=1;i<16;i++){
        bool g = dist[i] > cmax;
        cmax  = g ? dist[i] : cmax;
        cslot = g ? i : cslot;
      }
    }
  }
  int keep = -1;
  for (int r=0;r<16;r++){
    float lv = dist[0]; int li = didx[0], ls = 0;
    #pragma unroll
    for (int i=1;i<16;i++){
      bool lt = (dist[i] < lv) || (dist[i] == lv && didx[i] < li);
      lv = lt ? dist[i] : lv; li = lt ? didx[i] : li; ls = lt ? i : ls;
    }
    float gv = lv; int gi = li;
    #pragma unroll
    for (int off=32; off>=1; off>>=1){
      float ov = __shfl_xor(gv, off, 64);
      int   oi = __shfl_xor(gi, off, 64);
      if (ov < gv || (ov == gv && oi < gi)){ gv = ov; gi = oi; }
    }
    if (gi == li){
      #pragma unroll
      for (int i=0;i<16;i++) if (i == ls) dist[i] = 3.4e38f;   // static pop
    }
    if (lane == r) keep = gi;
  }
  if (lane < 16) knn[(size_t)widx*16 + lane] = keep;
}

// ---------------- flat GEMM: C(16384 x N) = A(16384x256,bf16) @ BT^T ----------------
template<int MODE>
__global__ __launch_bounds__(256) void k_gemm(
    const unsigned short* __restrict__ A, const unsigned short* __restrict__ BT,
    const float* __restrict__ bias0, const float* __restrict__ bias1,
    unsigned short* __restrict__ out0, unsigned short* __restrict__ out1,
    unsigned short* __restrict__ out2, const unsigned short* __restrict__ scbuf,
    float* __restrict__ fout){
  __shared__ unsigned short As[128*40];
  __shared__ unsigned short Bs[128*40];
  int m0 = blockIdx.x * 128, n0 = blockIdx.y * 128;
  int t = threadIdx.x;
  int lane = t & 63, wave = t >> 6, wm = wave >> 1, wn = wave & 1;
  int lrow = lane & 15, lkg = lane >> 4;
  f32x4 acc[4][4] = {};
  for (int k0 = 0; k0 < 256; k0 += 32){
    int r = t >> 1, h = t & 1;
    const bf16x8* ga = (const bf16x8*)(A  + (size_t)(m0 + r)*256 + k0 + h*16);
    const bf16x8* gb = (const bf16x8*)(BT + (size_t)(n0 + r)*256 + k0 + h*16);
    bf16x8 a0 = ga[0], a1 = ga[1], b0 = gb[0], b1 = gb[1];
    *(bf16x8*)&As[r*40 + h*16]     = a0;
    *(bf16x8*)&As[r*40 + h*16 + 8] = a1;
    *(bf16x8*)&Bs[r*40 + h*16]     = b0;
    *(bf16x8*)&Bs[r*40 + h*16 + 8] = b1;
    __syncthreads();
    bf16x8 af[4], bfr[4];
    #pragma unroll
    for (int fi=0; fi<4; fi++){
      af[fi]  = *(const bf16x8*)&As[(wm*64 + fi*16 + lrow)*40 + lkg*8];
      bfr[fi] = *(const bf16x8*)&Bs[(wn*64 + fi*16 + lrow)*40 + lkg*8];
    }
    #pragma unroll
    for (int fi=0; fi<4; fi++)
      #pragma unroll
      for (int nf=0; nf<4; nf++)
        acc[fi][nf] = MFMA(af[fi], bfr[nf], acc[fi][nf]);
    __syncthreads();
  }
  #pragma unroll
  for (int fi=0; fi<4; fi++)
    #pragma unroll
    for (int nf=0; nf<4; nf++)
      #pragma unroll
      for (int r=0; r<4; r++){
        int row = m0 + wm*64 + fi*16 + lkg*4 + r;
        int col = n0 + wn*64 + nf*16 + lrow;
        float v = acc[fi][nf][r];
        if (MODE == 0){
          if (col < 256) out0[(size_t)row*256 + col]       = f2bf(v + bias0[col]);
          else           out1[(size_t)row*256 + col - 256] = f2bf(v + bias1[col-256]);
        } else if (MODE == 1){
          if (col < 256)      out0[(size_t)row*256 + col]       = f2bf(v);
          else if (col < 512) out1[(size_t)row*256 + col - 256] = f2bf(v);
          else                out2[(size_t)row*256 + col - 512] = f2bf(v);
        } else {
          fout[(size_t)row*256 + col] = v + bias0[col] + bf2f(scbuf[(size_t)row*256 + col]);
        }
      }
}

// ================= stage C GEMM helper: 64-row LDS tile x global B^T ==============
__device__ __forceinline__ void mfma_pass64(const char* tileB, const unsigned short* __restrict__ BT,
                                            int lrow, int lkg, int colbase, f32x4 (&acc)[4][2]){
  for (int k0 = 0; k0 < 256; k0 += 32){
    bf16x8 af[4];
    #pragma unroll
    for (int fi=0; fi<4; fi++)
      af[fi] = *(const bf16x8*)(tileB + swz(fi*16 + lrow, k0*2 + lkg*16));
    bf16x8 bfr[2];
    #pragma unroll
    for (int nf=0; nf<2; nf++)
      bfr[nf] = *(const bf16x8*)(BT + (size_t)(colbase + nf*16 + lrow)*256 + k0 + lkg*8);
    #pragma unroll
    for (int fi=0; fi<4; fi++){
      acc[fi][0] = MFMA(af[fi], bfr[0], acc[fi][0]);
      acc[fi][1] = MFMA(af[fi], bfr[1], acc[fi][1]);
    }
  }
}

// ---------------- stage C: fused per-point transformer core ----------------
// 512 thr (8 waves), 4 points -> M=64 rows. wave w owns cols [32w,32w+32).
// Separate H (32KB) and A2 (32KB) tiles: H stays live for the late pe-GEMM;
// attn overwrites A2 in place (same-lane readback). Worst-phase live regs ~90.
// LDS 76KB -> 2 blocks/CU; launch_bounds(512,4) -> 128-reg budget, 16 waves/CU.
__global__ __launch_bounds__(512, 4) void k_stagec(
    const float* __restrict__ xyz, const int* __restrict__ knn,
    const unsigned short* __restrict__ qgbuf, const unsigned short* __restrict__ kgbuf,
    const unsigned short* __restrict__ vbuf,
    const unsigned short* __restrict__ BposT, const unsigned short* __restrict__ g2sT,
    const float* __restrict__ W1, const float* __restrict__ b1d,
    const float* __restrict__ b2d, const float* __restrict__ c1,
    const float* __restrict__ gb2,
    unsigned short* __restrict__ resbuf){
  extern __shared__ char smem[];
  char*           HsB   = smem;                              // 32KB H (rows 0-63), persists
  char*           A2sB  = smem + 32768;                      // 32KB a1 -> attn (in-place)
  unsigned short* qgs   = (unsigned short*)(smem + 65536);   // 2KB
  float*          rels  = (float*)(smem + 67584);            // 1KB (dead after phase1)
  float*          W1s   = (float*)(smem + 68608);            // 3KB (dead after phase1)
  unsigned short* resSb = (unsigned short*)(smem + 67584);   // 2KB bf16 (alias rels/W1s head)
  float*          b1s   = (float*)(smem + 71680);
  float*          c1s   = (float*)(smem + 72704);
  float*          b2s   = (float*)(smem + 73728);
  float*          gb2s  = (float*)(smem + 74752);
  int*            gidx  = (int*)(smem + 75776);              // 256B

  int t = threadIdx.x;
  int lane = t & 63, wn = t >> 6;
  int lrow = lane & 15, lkg = lane >> 4;
  int colbase = 32*wn;
  int tile = blockIdx.x;                  // 4096 tiles
  int b = tile >> 10;
  int n0 = (tile & 1023) * 4;
  int g0 = b*NPTS + n0;

  // ---- phase 0: stage small data ----
  for (int i = t; i < 768; i += 512) W1s[i] = W1[i];
  if (t < 256){ b1s[t] = b1d[t]; c1s[t] = c1[t]; b2s[t] = b2d[t]; gb2s[t] = gb2[t]*0.0625f; }
  if (t < 64){
    int p = t >> 4, kk = t & 15;
    int id = knn[(size_t)(g0 + p)*16 + kk];
    gidx[t] = b*NPTS + id;
    const float* cp  = xyz + (size_t)(b*NPTS + n0 + p)*3;
    const float* np_ = xyz + (size_t)(b*NPTS + id)*3;
    rels[t*4+0] = cp[0]-np_[0]; rels[t*4+1] = cp[1]-np_[1]; rels[t*4+2] = cp[2]-np_[2];
  }
  if (t < 256){ int e = t * 4; int p = e >> 8, c = e & 255;
    *(s16x4*)&qgs[e] = *(const s16x4*)&qgbuf[(size_t)(g0 + p)*256 + c]; }
  __syncthreads();

  // ---- phase 1: H = relu(rel @ W1 + b1)  (64 rows x 256 cols) ----
  {
    int r = t >> 3, c0 = (t & 7) * 32;
    float rx = rels[r*4], ry = rels[r*4+1], rz = rels[r*4+2];
    #pragma unroll
    for (int cc = 0; cc < 32; cc += 8){
      int c = c0 + cc;
      bf16x8 hv;
      #pragma unroll
      for (int j=0;j<8;j++){
        float h = rx*W1s[c+j] + ry*W1s[256+c+j] + rz*W1s[512+c+j] + b1s[c+j];
        hv[j] = (short)f2bf(fmaxf(h, 0.0f));
      }
      *(bf16x8*)(HsB + swz(r, c*2)) = hv;
    }
  }
  __syncthreads();                        // B1: H visible

  // ---- phase 2: posg = H @ W2g1 ; a1 = relu(posg + qg - kg + c1) -> A2 ----
  {
    f32x4 accg[4][2] = {};
    mfma_pass64(HsB, BposT, lrow, lkg, colbase, accg);
    #pragma unroll
    for (int fi=0; fi<4; fi++)
      #pragma unroll
      for (int nf=0; nf<2; nf++)
        #pragma unroll
        for (int r=0; r<4; r++){
          int row = fi*16 + lkg*4 + r;
          int col = colbase + nf*16 + lrow;
          float a1 = accg[fi][nf][r] + bf2f(qgs[fi*256 + col])
                   - bf2f(kgbuf[(size_t)gidx[row]*256 + col]) + c1s[col];
          *(unsigned short*)(A2sB + swz(row, col*2)) = f2bf(fmaxf(a1, 0.0f));
        }
  }
  __syncthreads();                        // B2: A2 visible

  // ---- phase 3: s = A2 @ (g2/16) ; softmax over K=16 ; attn -> A2 (in place) ----
  {
    f32x4 acc2[4][2] = {};
    mfma_pass64(A2sB, g2sT, lrow, lkg, colbase, acc2);
    __syncthreads();                      // B3: all A2 reads done before overwrite
    #pragma unroll
    for (int fi=0; fi<4; fi++)
      #pragma unroll
      for (int nf=0; nf<2; nf++){
        int col = colbase + nf*16 + lrow;
        float s[4], e[4];
        #pragma unroll
        for (int r=0;r<4;r++) s[r] = acc2[fi][nf][r] + gb2s[col];
        float mx = fmaxf(fmaxf(s[0],s[1]), fmaxf(s[2],s[3]));
        mx = fmaxf(mx, __shfl_xor(mx, 16, 64));
        mx = fmaxf(mx, __shfl_xor(mx, 32, 64));
        float sm = 0.f;
        #pragma unroll
        for (int r=0;r<4;r++){ e[r] = __expf(s[r]-mx); sm += e[r]; }
        sm += __shfl_xor(sm, 16, 64);
        sm += __shfl_xor(sm, 32, 64);
        float rs = 1.0f / sm;
        #pragma unroll
        for (int r=0;r<4;r++){
          int row = fi*16 + lkg*4 + r;
          *(unsigned short*)(A2sB + swz(row, col*2)) = f2bf(e[r]*rs);  // same-lane readback
        }
      }
  }

  // ---- phase 4: pe = H @ W2 (+b2); res = sum_k attn * (v + pe) ----
  {
    f32x4 acce[4][2] = {};
    mfma_pass64(HsB, BposT + (size_t)256*256, lrow, lkg, colbase, acce);
    #pragma unroll
    for (int fi=0; fi<4; fi++)
      #pragma unroll
      for (int nf=0; nf<2; nf++){
        int col = colbase + nf*16 + lrow;
        float tsum = 0.f;
        #pragma unroll
        for (int r=0;r<4;r++){
          int row = fi*16 + lkg*4 + r;
          float at = bf2f(*(unsigned short*)(A2sB + swz(row, col*2)));
          float vv = bf2f(vbuf[(size_t)gidx[row]*256 + col]) + acce[fi][nf][r] + b2s[col];
          tsum += at * vv;
        }
        tsum += __shfl_xor(tsum, 16, 64);
        tsum += __shfl_xor(tsum, 32, 64);
        if (lkg == 0) resSb[fi*256 + col] = f2bf(tsum);
      }
  }
  __syncthreads();                        // B4: resSb visible

  // ---- phase 5: store res (bf16, vectorized) ----
  if (t < 256){ int e = t * 4; int p = e >> 8, c = e & 255;
    *(s16x4*)&resbuf[(size_t)(g0 + p)*256 + c] = *(s16x4*)&resSb[e]; }
}

// ---------------- host ----------------
extern "C" void kernel_launch(void* const* d_in, const int* in_sizes, int n_in,
                              void* d_out, int out_size, void* d_ws, size_t ws_size,
                              hipStream_t stream){
  (void)in_sizes; (void)n_in; (void)out_size; (void)ws_size;
  const float* xyz  = (const float*)d_in[0];
  const float* feat = (const float*)d_in[1];
  const float* W1   = (const float*)d_in[2];
  const float* b1d  = (const float*)d_in[3];
  const float* W2   = (const float*)d_in[4];
  const float* b2d  = (const float*)d_in[5];
  const float* fc1w = (const float*)d_in[6];
  const float* fc1b = (const float*)d_in[7];
  const float* wq   = (const float*)d_in[8];
  const float* wk   = (const float*)d_in[9];
  const float* wv   = (const float*)d_in[10];
  const float* g1   = (const float*)d_in[11];
  const float* gb1  = (const float*)d_in[12];
  const float* g2   = (const float*)d_in[13];
  const float* gb2  = (const float*)d_in[14];
  const float* fc2w = (const float*)d_in[15];
  const float* fc2b = (const float*)d_in[16];
  const float* scw  = (const float*)d_in[17];
  const float* scb  = (const float*)d_in[18];

  char* ws = (char*)d_ws;
  size_t off = 0;
  auto alloc = [&](size_t bytes)->void*{ void* p = ws + off; off += (bytes + 255) & ~(size_t)255; return p; };
  int*            knn    = (int*)alloc((size_t)NTOT*16*4);
  unsigned short* Xb     = (unsigned short*)alloc((size_t)NTOT*256*2); // reused as res
  unsigned short* fbuf   = (unsigned short*)alloc((size_t)NTOT*256*2);
  unsigned short* qg     = (unsigned short*)alloc((size_t)NTOT*256*2);
  unsigned short* kg     = (unsigned short*)alloc((size_t)NTOT*256*2);
  unsigned short* vbuf   = (unsigned short*)alloc((size_t)NTOT*256*2);
  unsigned short* scbuf  = (unsigned short*)alloc((size_t)NTOT*256*2);
  unsigned short* fc1scT = (unsigned short*)alloc(512*256*2);
  unsigned short* qkvT   = (unsigned short*)alloc(768*256*2);
  unsigned short* BposT  = (unsigned short*)alloc(512*256*2);
  unsigned short* g2sT   = (unsigned short*)alloc(256*256*2);
  unsigned short* fc2T   = (unsigned short*)alloc(256*256*2);
  float*          c1     = (float*)alloc(256*4);
  unsigned short* res    = Xb;   // alias: Xb dead after B1

  k_convert<<<4096, 256, 0, stream>>>(feat, Xb, NTOT*256);
  k_prep_mats<<<256, 256, 0, stream>>>(fc1w, scw, wv, g2, fc2w, W2, fc1scT, qkvT, g2sT, fc2T, BposT);
  k_prep_gemm<<<769, 256, 0, stream>>>(wq, wk, g1, W2, b2d, gb1, qkvT, BposT, c1);
  k_knn<<<4096, 256, 0, stream>>>(xyz, knn);
  k_gemm<0><<<dim3(128,4), 256, 0, stream>>>(Xb, fc1scT, fc1b, scb, fbuf, scbuf, nullptr, nullptr, nullptr);
  k_gemm<1><<<dim3(128,6), 256, 0, stream>>>(fbuf, qkvT, nullptr, nullptr, qg, kg, vbuf, nullptr, nullptr);
  hipFuncSetAttribute((const void*)k_stagec, hipFuncAttributeMaxDynamicSharedMemorySize, 76032);
  k_stagec<<<4096, 512, 76032, stream>>>(xyz, knn, qg, kg, vbuf, BposT, g2sT, W1, b1d, b2d, c1, gb2, res);
  k_gemm<2><<<dim3(128,2), 256, 0, stream>>>(res, fc2T, fc2b, nullptr, nullptr, nullptr, nullptr, scbuf, (float*)d_out);
}